// Round 1
// baseline (63.015 us; speedup 1.0000x reference)
//
#include <hip/hip_runtime.h>

// Problem constants (from reference init_kwargs)
#define BB   64
#define KP   21
#define HH   256
#define KS   9
#define PADK 4   // KS/2

// One block per (b,k) point: writes the clipped 9x9 patch of 10*kernel2d
// centered at (r,c). out[p*H*H + i*H + j] = 10 * w[r-i+PAD][c-j+PAD].
__global__ void heatmap_patch_kernel(const int* __restrict__ x,
                                     const float* __restrict__ k2d,
                                     float* __restrict__ out) {
    const int p = blockIdx.x;        // 0 .. B*KP-1
    const int t = threadIdx.x;       // 0 .. 127 (81 useful)
    if (t >= KS * KS) return;

    const int r = x[2 * p];
    const int c = x[2 * p + 1];

    const int dy = t / KS;           // 0..8
    const int dx = t - dy * KS;      // 0..8
    const int i = r - PADK + dy;
    const int j = c - PADK + dx;
    if (i < 0 || i >= HH || j < 0 || j >= HH) return;

    // conv weight index: r - i + PAD = KS-1-dy ; c - j + PAD = KS-1-dx
    const float v = 10.0f * k2d[(KS - 1 - dy) * KS + (KS - 1 - dx)];
    out[(size_t)p * (HH * HH) + (size_t)i * HH + j] = v;
}

extern "C" void kernel_launch(void* const* d_in, const int* in_sizes, int n_in,
                              void* d_out, int out_size, void* d_ws, size_t ws_size,
                              hipStream_t stream) {
    const int*   x    = (const int*)d_in[0];    // [B, KP, 2] int32
    const float* k2d  = (const float*)d_in[1];  // [KS, KS] float32
    float*       out  = (float*)d_out;          // [B, KP, H, H] float32

    // 1) zero the whole output (write-BW bound, ~352 MB)
    hipMemsetAsync(out, 0, (size_t)out_size * sizeof(float), stream);

    // 2) scatter the 1344 Gaussian patches (negligible)
    heatmap_patch_kernel<<<BB * KP, 128, 0, stream>>>(x, k2d, out);
}